// Round 1
// baseline (980.355 us; speedup 1.0000x reference)
//
#include <hip/hip_runtime.h>
#include <hip/hip_bf16.h>
#include <stdint.h>

typedef __bf16 bf16_t;
typedef __attribute__((ext_vector_type(8))) __bf16 bf16x8;
typedef __attribute__((ext_vector_type(4))) __bf16 bf16x4;
typedef __attribute__((ext_vector_type(4))) float f32x4;

constexpr int IN_F   = 4096;
constexpr int OUT_F  = 4096;
constexpr int RANKC  = 12;
constexpr float SCAL = 16.0f / 12.0f;
constexpr int MTOT   = 4 * 4096;   // B*S = 16384

typedef __attribute__((address_space(1))) const unsigned int uint_g;
typedef __attribute__((address_space(3))) unsigned int uint_l;

__device__ __forceinline__ void gload_lds16(const void* g, void* l) {
    // async global->LDS, 16B per lane. LDS dest is wave-uniform base + lane*16,
    // which matches our linear per-lane addressing (chunk = 8 bf16 per lane).
    __builtin_amdgcn_global_load_lds((uint_g*)(uintptr_t)g,
                                     (uint_l*)(uintptr_t)l,
                                     16, 0, 0);
}

// ---------------------------------------------------------------------------
// Kernel 1: Wb[o,i] = bf16( W[o,i] + SCAL * sum_r P[o,r]*sigma[r]*Q[i,r] )
// 4 elements per thread; o is wave-uniform (scalar P loads).
// ---------------------------------------------------------------------------
__global__ __launch_bounds__(256) void fold_weight_kernel(
    const float* __restrict__ W, const float* __restrict__ P,
    const float* __restrict__ sg, const float* __restrict__ Q,
    bf16_t* __restrict__ Wb)
{
    const int t    = blockIdx.x * 256 + threadIdx.x;
    const int base = t * 4;                 // element index into [OUT_F*IN_F]
    const int o    = base >> 12;            // IN_F = 4096 = 2^12
    const int i0   = base & (IN_F - 1);

    float psig[RANKC];
#pragma unroll
    for (int r = 0; r < RANKC; ++r)
        psig[r] = P[o * RANKC + r] * sg[r] * SCAL;

    const float4 w = *reinterpret_cast<const float4*>(W + base);
    float out[4] = {w.x, w.y, w.z, w.w};
#pragma unroll
    for (int j = 0; j < 4; ++j) {
        const float* q = Q + (size_t)(i0 + j) * RANKC;
        float d = 0.0f;
#pragma unroll
        for (int r = 0; r < RANKC; ++r) d += psig[r] * q[r];
        out[j] += d;
    }
    bf16x4 ob;
#pragma unroll
    for (int j = 0; j < 4; ++j) ob[j] = (bf16_t)out[j];
    *reinterpret_cast<bf16x4*>(Wb + base) = ob;
}

// ---------------------------------------------------------------------------
// Kernel 2: x (fp32) -> bf16, 8 elements/thread
// ---------------------------------------------------------------------------
__global__ __launch_bounds__(256) void cvt_x_kernel(
    const float* __restrict__ X, bf16_t* __restrict__ Xb)
{
    const size_t base = ((size_t)blockIdx.x * 256 + threadIdx.x) * 8;
    const float4 a = *reinterpret_cast<const float4*>(X + base);
    const float4 b = *reinterpret_cast<const float4*>(X + base + 4);
    bf16x8 ob;
    ob[0] = (bf16_t)a.x; ob[1] = (bf16_t)a.y; ob[2] = (bf16_t)a.z; ob[3] = (bf16_t)a.w;
    ob[4] = (bf16_t)b.x; ob[5] = (bf16_t)b.y; ob[6] = (bf16_t)b.z; ob[7] = (bf16_t)b.w;
    *reinterpret_cast<bf16x8*>(Xb + base) = ob;
}

// ---------------------------------------------------------------------------
// Kernel 3: C[M,N] = A[M,K] * B[N,K]^T   (bf16 in, fp32 out)
// m97 structure: 128x128 tile, BK=64, 4 waves (2x2 of 64x64),
// global_load_lds width=16, mfma_f32_16x16x32_bf16.
// ---------------------------------------------------------------------------
constexpr int BM = 128, BN = 128, BK = 64;

__global__ __launch_bounds__(256) void gemm_bt_kernel(
    const bf16_t* __restrict__ A,   // [M, K]
    const bf16_t* __restrict__ B,   // [N, K]  (row = out-feature)
    float* __restrict__ C,          // [M, N]
    int M, int N, int K)
{
    __shared__ bf16_t sA[BM * BK];
    __shared__ bf16_t sB[BN * BK];

    const int tid  = threadIdx.x;
    const int lane = tid & 63;
    const int wave = tid >> 6;
    const int wr   = wave >> 1;     // 0..1
    const int wc   = wave & 1;      // 0..1

    // XCD-aware bijective swizzle (nwg = 4096, divisible by 8)
    const int nwg = gridDim.x;
    const int cpx = nwg >> 3;
    const int bid = blockIdx.x;
    const int swz = (bid & 7) * cpx + (bid >> 3);
    const int nbx = N / BN;
    const int brow = (swz / nbx) * BM;
    const int bcol = (swz % nbx) * BN;

    // staging: thread handles 4 chunks of 8 bf16 (16B), chunk j at elem e + j*2048
    const int e    = tid * 8;       // first chunk element offset
    const int srow = e >> 6;        // e / BK
    const int scol = e & (BK - 1);
    const bf16_t* aptr = A + (size_t)(brow + srow) * K + scol;
    const bf16_t* bptr = B + (size_t)(bcol + srow) * K + scol;

    f32x4 acc[4][4];
#pragma unroll
    for (int m = 0; m < 4; ++m)
#pragma unroll
        for (int n = 0; n < 4; ++n)
#pragma unroll
            for (int q = 0; q < 4; ++q) acc[m][n][q] = 0.0f;

    const int lr = lane & 15;            // fragment row (A) / col (B)
    const int lk = (lane >> 4) * 8;      // fragment k offset

    for (int k0 = 0; k0 < K; k0 += BK) {
#pragma unroll
        for (int j = 0; j < 4; ++j)
            gload_lds16(aptr + (size_t)j * 32 * K + k0, &sA[e + j * 2048]);
#pragma unroll
        for (int j = 0; j < 4; ++j)
            gload_lds16(bptr + (size_t)j * 32 * K + k0, &sB[e + j * 2048]);

        asm volatile("s_waitcnt vmcnt(0)" ::: "memory");
        __syncthreads();

#pragma unroll
        for (int kk = 0; kk < BK / 32; ++kk) {
            bf16x8 af[4], bq[4];
#pragma unroll
            for (int m = 0; m < 4; ++m)
                af[m] = *reinterpret_cast<const bf16x8*>(
                    &sA[(wr * 64 + m * 16 + lr) * BK + kk * 32 + lk]);
#pragma unroll
            for (int n = 0; n < 4; ++n)
                bq[n] = *reinterpret_cast<const bf16x8*>(
                    &sB[(wc * 64 + n * 16 + lr) * BK + kk * 32 + lk]);
#pragma unroll
            for (int m = 0; m < 4; ++m)
#pragma unroll
                for (int n = 0; n < 4; ++n)
                    acc[m][n] = __builtin_amdgcn_mfma_f32_16x16x32_bf16(
                        af[m], bq[n], acc[m][n], 0, 0, 0);
        }
        __syncthreads();
    }

    // epilogue: D col = lane&15, row = (lane>>4)*4 + reg   [m89-verified]
    const int r0 = brow + wr * 64 + (lane >> 4) * 4;
    const int c0 = bcol + wc * 64 + lr;
#pragma unroll
    for (int m = 0; m < 4; ++m)
#pragma unroll
        for (int n = 0; n < 4; ++n)
#pragma unroll
            for (int q = 0; q < 4; ++q)
                C[(size_t)(r0 + m * 16 + q) * N + (c0 + n * 16)] = acc[m][n][q];
}

// ---------------------------------------------------------------------------
extern "C" void kernel_launch(void* const* d_in, const int* in_sizes, int n_in,
                              void* d_out, int out_size, void* d_ws, size_t ws_size,
                              hipStream_t stream)
{
    const float* x      = (const float*)d_in[0];   // [4,4096,4096]
    const float* weight = (const float*)d_in[1];   // [4096,4096] (out,in)
    const float* loraP  = (const float*)d_in[2];   // [4096,12]
    const float* sigma  = (const float*)d_in[3];   // [12]
    const float* loraQ  = (const float*)d_in[4];   // [4096,12]
    float* out = (float*)d_out;

    bf16_t* Wb = (bf16_t*)d_ws;                                    // 32 MiB
    bf16_t* Xb = (bf16_t*)((char*)d_ws + (size_t)OUT_F * IN_F * 2); // 128 MiB

    // 1) fold LoRA into weight, convert to bf16
    fold_weight_kernel<<<(OUT_F * IN_F) / (256 * 4), 256, 0, stream>>>(
        weight, loraP, sigma, loraQ, Wb);

    // 2) x -> bf16
    cvt_x_kernel<<<((size_t)MTOT * IN_F) / (256 * 8), 256, 0, stream>>>(x, Xb);

    // 3) GEMM: out = Xb @ Wb^T
    const int nwg = (MTOT / BM) * (OUT_F / BN);   // 128 * 32 = 4096
    gemm_bt_kernel<<<nwg, 256, 0, stream>>>(Xb, Wb, out, MTOT, OUT_F, IN_F);
}

// Round 2
// 616.014 us; speedup vs baseline: 1.5914x; 1.5914x over previous
//
#include <hip/hip_runtime.h>
#include <hip/hip_bf16.h>
#include <stdint.h>

typedef __bf16 bf16_t;
typedef __attribute__((ext_vector_type(8))) __bf16 bf16x8;
typedef __attribute__((ext_vector_type(4))) __bf16 bf16x4;
typedef __attribute__((ext_vector_type(4))) float f32x4;

constexpr int IN_F   = 4096;
constexpr int OUT_F  = 4096;
constexpr int RANKC  = 12;
constexpr float SCAL = 16.0f / 12.0f;
constexpr int MTOT   = 4 * 4096;   // B*S = 16384
constexpr int NT     = IN_F / 64;  // 64 K-tiles

typedef __attribute__((address_space(1))) const unsigned int uint_g;
typedef __attribute__((address_space(3))) unsigned int uint_l;

__device__ __forceinline__ void gload_lds16(const void* g, void* l) {
    __builtin_amdgcn_global_load_lds((uint_g*)(uintptr_t)g,
                                     (uint_l*)(uintptr_t)l,
                                     16, 0, 0);
}

// ---------------------------------------------------------------------------
// Kernel 1: Wb[o,i] = bf16( W[o,i] + SCAL * sum_r P[o,r]*sigma[r]*Q[i,r] )
// ---------------------------------------------------------------------------
__global__ __launch_bounds__(256) void fold_weight_kernel(
    const float* __restrict__ W, const float* __restrict__ P,
    const float* __restrict__ sg, const float* __restrict__ Q,
    bf16_t* __restrict__ Wb)
{
    const int t    = blockIdx.x * 256 + threadIdx.x;
    const int base = t * 4;
    const int o    = base >> 12;
    const int i0   = base & (IN_F - 1);

    float psig[RANKC];
#pragma unroll
    for (int r = 0; r < RANKC; ++r)
        psig[r] = P[o * RANKC + r] * sg[r] * SCAL;

    const float4 w = *reinterpret_cast<const float4*>(W + base);
    float out[4] = {w.x, w.y, w.z, w.w};
#pragma unroll
    for (int j = 0; j < 4; ++j) {
        const float* q = Q + (size_t)(i0 + j) * RANKC;
        float d = 0.0f;
#pragma unroll
        for (int r = 0; r < RANKC; ++r) d += psig[r] * q[r];
        out[j] += d;
    }
    bf16x4 ob;
#pragma unroll
    for (int j = 0; j < 4; ++j) ob[j] = (bf16_t)out[j];
    *reinterpret_cast<bf16x4*>(Wb + base) = ob;
}

// ---------------------------------------------------------------------------
// Kernel 2: x (fp32) -> bf16
// ---------------------------------------------------------------------------
__global__ __launch_bounds__(256) void cvt_x_kernel(
    const float* __restrict__ X, bf16_t* __restrict__ Xb)
{
    const size_t base = ((size_t)blockIdx.x * 256 + threadIdx.x) * 8;
    const float4 a = *reinterpret_cast<const float4*>(X + base);
    const float4 b = *reinterpret_cast<const float4*>(X + base + 4);
    bf16x8 ob;
    ob[0] = (bf16_t)a.x; ob[1] = (bf16_t)a.y; ob[2] = (bf16_t)a.z; ob[3] = (bf16_t)a.w;
    ob[4] = (bf16_t)b.x; ob[5] = (bf16_t)b.y; ob[6] = (bf16_t)b.z; ob[7] = (bf16_t)b.w;
    *reinterpret_cast<bf16x8*>(Xb + base) = ob;
}

// ---------------------------------------------------------------------------
// Kernel 3: 256x256-tile 4-phase pipelined GEMM, C = A[M,K] * B[N,K]^T
//
// LDS tile layout (per operand, per buffer): logical (row, c16-chunk) at
// element offset row*64 + (c16 ^ (row&7))*8  -- 8-slot XOR swizzle, closed
// within each row, so row-subset staging regions are swizzle-closed.
// global_load_lds writes linearly (base + tid*16B); the global SOURCE is
// inverse-permuted so swizzled data lands correctly (rule #21).
//
// Staging map per K-tile t (2 loads per stage64 pair; B-full = 4):
//   p1 (kk0,mh0): stage B(t+1)      -> buf[(t+1)&1]   (B reads done by p2)
//   p2 (kk1,mh0): stage A-H1(t+1)   -> buf[(t+1)&1]   (rows 64-127,192-255)
//   p3 (kk0,mh1): stage A-H0(t+2)   -> buf[t&1]       (rows 0-63,128-191;
//                                      tile t's A-H0 reads finished in p2)
//   p4 (kk1,mh1): no stage
// Uniform counted s_waitcnt vmcnt(4) per phase guarantees each region is
// resident exactly when first read; never drains to 0 in the main loop.
// ---------------------------------------------------------------------------
__device__ __forceinline__ void stage64(const bf16_t* __restrict__ g, size_t grow0,
                                        bf16_t* lt, int ldrow0, int kt, int tid)
{
    const int rr  = tid >> 3;                       // 0..63 within region
    const int c16 = (tid & 7) ^ (rr & 7);           // inverse-swizzled source chunk
    const bf16_t* src = g + (grow0 + (size_t)(ldrow0 + rr)) * IN_F + kt * 64 + c16 * 8;
    gload_lds16(src, lt + ldrow0 * 64 + tid * 8);   // linear LDS dest
}

#define PH(KK, MH, READB, CA_, CB_, ...) do {                                   \
    bf16x8 af[4];                                                               \
    const int slot_ = (((KK) * 4 + hi) ^ (lr & 7)) * 8;                         \
    _Pragma("unroll")                                                           \
    for (int m = 0; m < 4; ++m)                                                 \
        af[m] = *(const bf16x8*)&CA_[(wm * 128 + (MH) * 64 + m * 16 + lr) * 64 + slot_]; \
    if (READB) {                                                                \
        _Pragma("unroll")                                                       \
        for (int n = 0; n < 4; ++n)                                             \
            bq[KK][n] = *(const bf16x8*)&CB_[(wn * 64 + n * 16 + lr) * 64 + slot_]; \
    }                                                                           \
    __VA_ARGS__                                                                 \
    __builtin_amdgcn_s_barrier();                                               \
    asm volatile("s_waitcnt lgkmcnt(0)" ::: "memory");                          \
    __builtin_amdgcn_sched_barrier(0);                                          \
    __builtin_amdgcn_s_setprio(1);                                              \
    _Pragma("unroll")                                                           \
    for (int m = 0; m < 4; ++m)                                                 \
        _Pragma("unroll")                                                       \
        for (int n = 0; n < 4; ++n)                                             \
            acc[(MH) * 4 + m][n] = __builtin_amdgcn_mfma_f32_16x16x32_bf16(     \
                af[m], bq[KK][n], acc[(MH) * 4 + m][n], 0, 0, 0);               \
    __builtin_amdgcn_s_setprio(0);                                              \
    asm volatile("s_waitcnt vmcnt(4)" ::: "memory");                            \
    __builtin_amdgcn_s_barrier();                                               \
    __builtin_amdgcn_sched_barrier(0);                                          \
} while (0)

#define TILE(T, CA_, CB_, NA_, NB_) do {                                        \
    const int t1_ = ((T) + 1 < NT) ? (T) + 1 : NT - 1;                          \
    const int t2_ = ((T) + 2 < NT) ? (T) + 2 : NT - 1;                          \
    PH(0, 0, 1, CA_, CB_,                                                       \
        stage64(Bm, bcol, NB_, 0,   t1_, tid);                                  \
        stage64(Bm, bcol, NB_, 64,  t1_, tid);                                  \
        stage64(Bm, bcol, NB_, 128, t1_, tid);                                  \
        stage64(Bm, bcol, NB_, 192, t1_, tid); );                               \
    PH(1, 0, 1, CA_, CB_,                                                       \
        stage64(Am, brow, NA_, 64,  t1_, tid);                                  \
        stage64(Am, brow, NA_, 192, t1_, tid); );                               \
    PH(0, 1, 0, CA_, CB_,                                                       \
        stage64(Am, brow, CA_, 0,   t2_, tid);                                  \
        stage64(Am, brow, CA_, 128, t2_, tid); );                               \
    PH(1, 1, 0, CA_, CB_, );                                                    \
} while (0)

__global__ __launch_bounds__(512, 2) void gemm256_kernel(
    const bf16_t* __restrict__ Am,   // [MTOT, IN_F]
    const bf16_t* __restrict__ Bm,   // [OUT_F, IN_F]
    float* __restrict__ C)           // [MTOT, OUT_F]
{
    __shared__ bf16_t sA0[256 * 64], sB0[256 * 64], sA1[256 * 64], sB1[256 * 64];

    const int tid  = threadIdx.x;
    const int lane = tid & 63;
    const int lr   = lane & 15;
    const int hi   = lane >> 4;
    const int wave = tid >> 6;
    const int wm   = wave >> 2;      // 0..1
    const int wn   = wave & 3;       // 0..3

    // XCD-aware bijective swizzle (nwg = 1024, % 8 == 0)
    const int bid = blockIdx.x;
    const int swz = (bid & 7) * 128 + (bid >> 3);
    const size_t brow = (size_t)(swz >> 4) * 256;   // 64 row-blocks
    const size_t bcol = (size_t)(swz & 15) * 256;   // 16 col-blocks

    f32x4 acc[8][4];
#pragma unroll
    for (int i = 0; i < 8; ++i)
#pragma unroll
        for (int n = 0; n < 4; ++n)
#pragma unroll
            for (int q = 0; q < 4; ++q) acc[i][n][q] = 0.0f;

    bf16x8 bq[2][4];

    // Prologue: order matters for the vmcnt accounting.
    stage64(Am, brow, sA0, 0,   0, tid);   // A-H0(0)
    stage64(Am, brow, sA0, 128, 0, tid);
    stage64(Bm, bcol, sB0, 0,   0, tid);   // B(0)
    stage64(Bm, bcol, sB0, 64,  0, tid);
    stage64(Bm, bcol, sB0, 128, 0, tid);
    stage64(Bm, bcol, sB0, 192, 0, tid);
    stage64(Am, brow, sA0, 64,  0, tid);   // A-H1(0)
    stage64(Am, brow, sA0, 192, 0, tid);
    stage64(Am, brow, sA1, 0,   1, tid);   // A-H0(1)
    stage64(Am, brow, sA1, 128, 1, tid);
    asm volatile("s_waitcnt vmcnt(2)" ::: "memory");   // first 8 (tile 0) landed
    __builtin_amdgcn_s_barrier();
    __builtin_amdgcn_sched_barrier(0);

    for (int tt = 0; tt < NT; tt += 2) {
        TILE(tt,     sA0, sB0, sA1, sB1);
        TILE(tt + 1, sA1, sB1, sA0, sB0);
    }

    // Epilogue: D col = lane&15, row = (lane>>4)*4 + reg  [m89-verified]
    const size_t r0 = brow + (size_t)wm * 128 + hi * 4;
    const size_t c0 = bcol + (size_t)wn * 64 + lr;
#pragma unroll
    for (int mi = 0; mi < 8; ++mi)
#pragma unroll
        for (int n = 0; n < 4; ++n)
#pragma unroll
            for (int q = 0; q < 4; ++q)
                C[(r0 + mi * 16 + q) * OUT_F + c0 + n * 16] = acc[mi][n][q];
}

// ---------------------------------------------------------------------------
extern "C" void kernel_launch(void* const* d_in, const int* in_sizes, int n_in,
                              void* d_out, int out_size, void* d_ws, size_t ws_size,
                              hipStream_t stream)
{
    const float* x      = (const float*)d_in[0];
    const float* weight = (const float*)d_in[1];
    const float* loraP  = (const float*)d_in[2];
    const float* sigma  = (const float*)d_in[3];
    const float* loraQ  = (const float*)d_in[4];
    float* out = (float*)d_out;

    bf16_t* Wb = (bf16_t*)d_ws;                                      // 32 MiB
    bf16_t* Xb = (bf16_t*)((char*)d_ws + (size_t)OUT_F * IN_F * 2);  // 128 MiB

    fold_weight_kernel<<<(OUT_F * IN_F) / (256 * 4), 256, 0, stream>>>(
        weight, loraP, sigma, loraQ, Wb);

    cvt_x_kernel<<<((size_t)MTOT * IN_F) / (256 * 8), 256, 0, stream>>>(x, Xb);

    gemm256_kernel<<<(MTOT / 256) * (OUT_F / 256), 512, 0, stream>>>(Xb, Wb, out);
}

// Round 3
// 609.712 us; speedup vs baseline: 1.6079x; 1.0103x over previous
//
#include <hip/hip_runtime.h>
#include <hip/hip_bf16.h>
#include <stdint.h>

typedef __bf16 bf16_t;
typedef __attribute__((ext_vector_type(8))) __bf16 bf16x8;
typedef __attribute__((ext_vector_type(4))) __bf16 bf16x4;
typedef __attribute__((ext_vector_type(4))) float f32x4;

constexpr int IN_F   = 4096;
constexpr int OUT_F  = 4096;
constexpr int RANKC  = 12;
constexpr float SCAL = 16.0f / 12.0f;
constexpr int MTOT   = 4 * 4096;   // B*S = 16384
constexpr int NT     = IN_F / 64;  // 64 K-tiles

typedef __attribute__((address_space(1))) const unsigned int uint_g;
typedef __attribute__((address_space(3))) unsigned int uint_l;

__device__ __forceinline__ void gload_lds16(const void* g, void* l) {
    __builtin_amdgcn_global_load_lds((uint_g*)(uintptr_t)g,
                                     (uint_l*)(uintptr_t)l,
                                     16, 0, 0);
}

// ---------------------------------------------------------------------------
// Kernel 1: Wb[o,i] = bf16( W[o,i] + SCAL * sum_r P[o,r]*sigma[r]*Q[i,r] )
// ---------------------------------------------------------------------------
__global__ __launch_bounds__(256) void fold_weight_kernel(
    const float* __restrict__ W, const float* __restrict__ P,
    const float* __restrict__ sg, const float* __restrict__ Q,
    bf16_t* __restrict__ Wb)
{
    const int t    = blockIdx.x * 256 + threadIdx.x;
    const int base = t * 4;
    const int o    = base >> 12;
    const int i0   = base & (IN_F - 1);

    float psig[RANKC];
#pragma unroll
    for (int r = 0; r < RANKC; ++r)
        psig[r] = P[o * RANKC + r] * sg[r] * SCAL;

    const float4 w = *reinterpret_cast<const float4*>(W + base);
    float out[4] = {w.x, w.y, w.z, w.w};
#pragma unroll
    for (int j = 0; j < 4; ++j) {
        const float* q = Q + (size_t)(i0 + j) * RANKC;
        float d = 0.0f;
#pragma unroll
        for (int r = 0; r < RANKC; ++r) d += psig[r] * q[r];
        out[j] += d;
    }
    bf16x4 ob;
#pragma unroll
    for (int j = 0; j < 4; ++j) ob[j] = (bf16_t)out[j];
    *reinterpret_cast<bf16x4*>(Wb + base) = ob;
}

// ---------------------------------------------------------------------------
// Kernel 2: x (fp32) -> bf16
// ---------------------------------------------------------------------------
__global__ __launch_bounds__(256) void cvt_x_kernel(
    const float* __restrict__ X, bf16_t* __restrict__ Xb)
{
    const size_t base = ((size_t)blockIdx.x * 256 + threadIdx.x) * 8;
    const float4 a = *reinterpret_cast<const float4*>(X + base);
    const float4 b = *reinterpret_cast<const float4*>(X + base + 4);
    bf16x8 ob;
    ob[0] = (bf16_t)a.x; ob[1] = (bf16_t)a.y; ob[2] = (bf16_t)a.z; ob[3] = (bf16_t)a.w;
    ob[4] = (bf16_t)b.x; ob[5] = (bf16_t)b.y; ob[6] = (bf16_t)b.z; ob[7] = (bf16_t)b.w;
    *reinterpret_cast<bf16x8*>(Xb + base) = ob;
}

// ---------------------------------------------------------------------------
// Kernel 3: 256x256-tile 4-phase pipelined GEMM, C = A[M,K] * B[N,K]^T
//
// LDS swizzle unchanged (8-slot XOR, row-closed; linear gload_lds dest +
// inverse-permuted global source, rule #21).
//
// Rebalanced stage map (2 loads EVERY phase) + maximal-slack waits
// (hazard-traced; only 2 vmcnt waits per K-tile, never drained):
//   p1 (kk0,mh0): stage B{0,64}(t+1)    reads: A-H0(t) kk0, B(t) kk0
//   p2 (kk1,mh0): stage B{128,192}(t+1) reads: A-H0(t) kk1, B(t) kk1
//                 W1 = vmcnt(6)  [guards A-H1(t), issued p3(t-1); newer:
//                                 A-H0(t+1) 2 + B(t+1) 4 = 6]
//   p3 (kk0,mh1): stage A-H1(t+1)       reads: A-H1(t) kk0 (B in regs)
//   p4 (kk1,mh1): stage A-H0(t+2)       reads: A-H1(t) kk1
//                 W2 = vmcnt(4)  [guards A-H0(t+1)+B(t+1); newer:
//                                 A-H1(t+1) 2 + A-H0(t+2) 2 = 4]
// Clamped tail stages still issue, so the vmcnt accounting stays exact.
// ---------------------------------------------------------------------------
__device__ __forceinline__ void stage64(const bf16_t* __restrict__ g, size_t grow0,
                                        bf16_t* lt, int ldrow0, int kt, int tid)
{
    const int rr  = tid >> 3;                       // 0..63 within region
    const int c16 = (tid & 7) ^ (rr & 7);           // inverse-swizzled source chunk
    const bf16_t* src = g + (grow0 + (size_t)(ldrow0 + rr)) * IN_F + kt * 64 + c16 * 8;
    gload_lds16(src, lt + ldrow0 * 64 + tid * 8);   // linear LDS dest
}

#define VMW(N) asm volatile("s_waitcnt vmcnt(" #N ")" ::: "memory")

#define PH(KK, MH, READB, CA_, CB_, WAITST, ...) do {                           \
    bf16x8 af[4];                                                               \
    const int slot_ = (((KK) * 4 + hi) ^ (lr & 7)) * 8;                         \
    _Pragma("unroll")                                                           \
    for (int m = 0; m < 4; ++m)                                                 \
        af[m] = *(const bf16x8*)&CA_[(wm * 128 + (MH) * 64 + m * 16 + lr) * 64 + slot_]; \
    if (READB) {                                                                \
        _Pragma("unroll")                                                       \
        for (int n = 0; n < 4; ++n)                                             \
            bq[KK][n] = *(const bf16x8*)&CB_[(wn * 64 + n * 16 + lr) * 64 + slot_]; \
    }                                                                           \
    __VA_ARGS__                                                                 \
    __builtin_amdgcn_s_barrier();                                               \
    asm volatile("s_waitcnt lgkmcnt(0)" ::: "memory");                          \
    __builtin_amdgcn_sched_barrier(0);                                          \
    __builtin_amdgcn_s_setprio(1);                                              \
    _Pragma("unroll")                                                           \
    for (int m = 0; m < 4; ++m)                                                 \
        _Pragma("unroll")                                                       \
        for (int n = 0; n < 4; ++n)                                             \
            acc[(MH) * 4 + m][n] = __builtin_amdgcn_mfma_f32_16x16x32_bf16(     \
                af[m], bq[KK][n], acc[(MH) * 4 + m][n], 0, 0, 0);               \
    __builtin_amdgcn_s_setprio(0);                                              \
    WAITST;                                                                     \
    __builtin_amdgcn_s_barrier();                                               \
    __builtin_amdgcn_sched_barrier(0);                                          \
} while (0)

#define TILE(T, CA_, CB_, NA_, NB_) do {                                        \
    const int t1_ = ((T) + 1 < NT) ? (T) + 1 : NT - 1;                          \
    const int t2_ = ((T) + 2 < NT) ? (T) + 2 : NT - 1;                          \
    PH(0, 0, 1, CA_, CB_, ,                                                     \
        stage64(Bm, bcol, NB_, 0,   t1_, tid);                                  \
        stage64(Bm, bcol, NB_, 64,  t1_, tid); );                               \
    PH(1, 0, 1, CA_, CB_, VMW(6),                                               \
        stage64(Bm, bcol, NB_, 128, t1_, tid);                                  \
        stage64(Bm, bcol, NB_, 192, t1_, tid); );                               \
    PH(0, 1, 0, CA_, CB_, ,                                                     \
        stage64(Am, brow, NA_, 64,  t1_, tid);                                  \
        stage64(Am, brow, NA_, 192, t1_, tid); );                               \
    PH(1, 1, 0, CA_, CB_, VMW(4),                                               \
        stage64(Am, brow, CA_, 0,   t2_, tid);                                  \
        stage64(Am, brow, CA_, 128, t2_, tid); );                               \
} while (0)

__global__ __launch_bounds__(512, 2) void gemm256_kernel(
    const bf16_t* __restrict__ Am,   // [MTOT, IN_F]
    const bf16_t* __restrict__ Bm,   // [OUT_F, IN_F]
    float* __restrict__ C)           // [MTOT, OUT_F]
{
    __shared__ bf16_t sA0[256 * 64], sB0[256 * 64], sA1[256 * 64], sB1[256 * 64];

    const int tid  = threadIdx.x;
    const int lane = tid & 63;
    const int lr   = lane & 15;
    const int hi   = lane >> 4;
    const int wave = tid >> 6;
    const int wm   = wave >> 2;      // 0..1
    const int wn   = wave & 3;       // 0..3

    // XCD-aware bijective swizzle (nwg = 1024, % 8 == 0)
    const int bid = blockIdx.x;
    const int swz = (bid & 7) * 128 + (bid >> 3);
    const size_t brow = (size_t)(swz >> 4) * 256;   // 64 row-blocks
    const size_t bcol = (size_t)(swz & 15) * 256;   // 16 col-blocks

    f32x4 acc[8][4];
#pragma unroll
    for (int i = 0; i < 8; ++i)
#pragma unroll
        for (int n = 0; n < 4; ++n)
#pragma unroll
            for (int q = 0; q < 4; ++q) acc[i][n][q] = 0.0f;

    bf16x8 bq[2][4];

    // Prologue: queue entering p1(0) must equal steady state
    // [A-H1(0) 2, A-H0(1) 2 in flight; A-H0(0)+B(0) resident].
    stage64(Am, brow, sA0, 0,   0, tid);   // A-H0(0)
    stage64(Am, brow, sA0, 128, 0, tid);
    stage64(Bm, bcol, sB0, 0,   0, tid);   // B(0)
    stage64(Bm, bcol, sB0, 64,  0, tid);
    stage64(Bm, bcol, sB0, 128, 0, tid);
    stage64(Bm, bcol, sB0, 192, 0, tid);
    stage64(Am, brow, sA0, 64,  0, tid);   // A-H1(0)
    stage64(Am, brow, sA0, 192, 0, tid);
    stage64(Am, brow, sA1, 0,   1, tid);   // A-H0(1)
    stage64(Am, brow, sA1, 128, 1, tid);
    VMW(4);
    __builtin_amdgcn_s_barrier();
    __builtin_amdgcn_sched_barrier(0);

    for (int tt = 0; tt < NT; tt += 2) {
        TILE(tt,     sA0, sB0, sA1, sB1);
        TILE(tt + 1, sA1, sB1, sA0, sB0);
    }

    // Epilogue: D col = lane&15, row = (lane>>4)*4 + reg  [m89-verified]
    const size_t r0 = brow + (size_t)wm * 128 + hi * 4;
    const size_t c0 = bcol + (size_t)wn * 64 + lr;
#pragma unroll
    for (int mi = 0; mi < 8; ++mi)
#pragma unroll
        for (int n = 0; n < 4; ++n)
#pragma unroll
            for (int q = 0; q < 4; ++q)
                C[(r0 + mi * 16 + q) * OUT_F + c0 + n * 16] = acc[mi][n][q];
}

// ---------------------------------------------------------------------------
extern "C" void kernel_launch(void* const* d_in, const int* in_sizes, int n_in,
                              void* d_out, int out_size, void* d_ws, size_t ws_size,
                              hipStream_t stream)
{
    const float* x      = (const float*)d_in[0];
    const float* weight = (const float*)d_in[1];
    const float* loraP  = (const float*)d_in[2];
    const float* sigma  = (const float*)d_in[3];
    const float* loraQ  = (const float*)d_in[4];
    float* out = (float*)d_out;

    bf16_t* Wb = (bf16_t*)d_ws;                                      // 32 MiB
    bf16_t* Xb = (bf16_t*)((char*)d_ws + (size_t)OUT_F * IN_F * 2);  // 128 MiB

    fold_weight_kernel<<<(OUT_F * IN_F) / (256 * 4), 256, 0, stream>>>(
        weight, loraP, sigma, loraQ, Wb);

    cvt_x_kernel<<<((size_t)MTOT * IN_F) / (256 * 8), 256, 0, stream>>>(x, Xb);

    gemm256_kernel<<<(MTOT / 256) * (OUT_F / 256), 512, 0, stream>>>(Xb, Wb, out);
}

// Round 5
// 606.621 us; speedup vs baseline: 1.6161x; 1.0051x over previous
//
#include <hip/hip_runtime.h>
#include <hip/hip_bf16.h>
#include <stdint.h>

typedef __bf16 bf16_t;
typedef __attribute__((ext_vector_type(8))) __bf16 bf16x8;
typedef __attribute__((ext_vector_type(4))) __bf16 bf16x4;
typedef __attribute__((ext_vector_type(4))) float f32x4;

constexpr int IN_F   = 4096;
constexpr int OUT_F  = 4096;
constexpr int RANKC  = 12;
constexpr float SCAL = 16.0f / 12.0f;
constexpr int MTOT   = 4 * 4096;   // B*S = 16384
constexpr int NT     = IN_F / 64;  // 64 K-tiles

typedef __attribute__((address_space(1))) const unsigned int uint_g;
typedef __attribute__((address_space(3))) unsigned int uint_l;

__device__ __forceinline__ void gload_lds16(const void* g, void* l) {
    __builtin_amdgcn_global_load_lds((uint_g*)(uintptr_t)g,
                                     (uint_l*)(uintptr_t)l,
                                     16, 0, 0);
}

// ---------------------------------------------------------------------------
// Kernel 1: Wb[o,i] = bf16( W[o,i] + SCAL * sum_r P[o,r]*sigma[r]*Q[i,r] )
// ---------------------------------------------------------------------------
__global__ __launch_bounds__(256) void fold_weight_kernel(
    const float* __restrict__ W, const float* __restrict__ P,
    const float* __restrict__ sg, const float* __restrict__ Q,
    bf16_t* __restrict__ Wb)
{
    const int t    = blockIdx.x * 256 + threadIdx.x;
    const int base = t * 4;
    const int o    = base >> 12;
    const int i0   = base & (IN_F - 1);

    float psig[RANKC];
#pragma unroll
    for (int r = 0; r < RANKC; ++r)
        psig[r] = P[o * RANKC + r] * sg[r] * SCAL;

    const float4 w = *reinterpret_cast<const float4*>(W + base);
    float out[4] = {w.x, w.y, w.z, w.w};
#pragma unroll
    for (int j = 0; j < 4; ++j) {
        const float* q = Q + (size_t)(i0 + j) * RANKC;
        float d = 0.0f;
#pragma unroll
        for (int r = 0; r < RANKC; ++r) d += psig[r] * q[r];
        out[j] += d;
    }
    bf16x4 ob;
#pragma unroll
    for (int j = 0; j < 4; ++j) ob[j] = (bf16_t)out[j];
    *reinterpret_cast<bf16x4*>(Wb + base) = ob;
}

// ---------------------------------------------------------------------------
// Kernel 2: x (fp32) -> bf16
// ---------------------------------------------------------------------------
__global__ __launch_bounds__(256) void cvt_x_kernel(
    const float* __restrict__ X, bf16_t* __restrict__ Xb)
{
    const size_t base = ((size_t)blockIdx.x * 256 + threadIdx.x) * 8;
    const float4 a = *reinterpret_cast<const float4*>(X + base);
    const float4 b = *reinterpret_cast<const float4*>(X + base + 4);
    bf16x8 ob;
    ob[0] = (bf16_t)a.x; ob[1] = (bf16_t)a.y; ob[2] = (bf16_t)a.z; ob[3] = (bf16_t)a.w;
    ob[4] = (bf16_t)b.x; ob[5] = (bf16_t)b.y; ob[6] = (bf16_t)b.z; ob[7] = (bf16_t)b.w;
    *reinterpret_cast<bf16x8*>(Xb + base) = ob;
}

// ---------------------------------------------------------------------------
// Kernel 3: 256x256 4-phase pipelined GEMM, register-prefetched fragments.
// RACE-SAFE rule: every ds_read at a phase HEAD reads a region whose staging
// loads were drained by a VMW in an EARLIER phase followed by a barrier
// (all-waves guarantee). Per-wave vmcnt is never used to justify reading
// other waves' staged rows (the round-4 bug).
//
// Phase layout (1 barrier per phase):
//   pN: [stage 2 loads] [head ds_reads for p(N+1)] [MFMA from regs read at
//       p(N-1) head] [counted VMW] BAR SB
//
// Stage map: p1 B(t+1){0,64}  p2 B(t+1){128,192}  p3 A-H1(t+1)  p4 A-H0(t+2)
// Head reads: p1 afB<-A-H0(t).kk1, bq1<-B(t).kk1   (drained p2/p3 of t-1)
//             p2 afA<-A-H1(t).kk0                  (drained p1(t) VMW(4))
//             p3 afB<-A-H1(t).kk1                  (same)
//             p4 afA<-A-H0(t+1).kk0 [NA_], bq0<-B(t+1).kk0 [NB_]
//                                    (drained p2(t) VMW(4) + p3(t) VMW(2))
// Queue trace (steady): p1 start 4 [A-H1(t)2, A-H0(t+1)2] +2 VMW(4)->4;
//   p2 +2=6 VMW(4)->4 [B(t+1)4]; p3 +2=6 VMW(2)->2 [A-H1(t+1)2];
//   p4 +2=4 no-wait -> matches p1 start. Never drained to 0.
// WAR safety: a region's last ds_reads complete (lgkm-waited) >=1 barrier
// before any stage write to it is issued; within-phase stage targets are
// disjoint from within-phase read targets (checked per phase).
// Tail clamp re-stages tile NT-1 data into dead buffers; counts preserved.
// ---------------------------------------------------------------------------
__device__ __forceinline__ void stage64(const bf16_t* __restrict__ g, size_t grow0,
                                        bf16_t* lt, int ldrow0, int kt, int tid)
{
    const int rr  = tid >> 3;                       // 0..63 within region
    const int c16 = (tid & 7) ^ (rr & 7);           // inverse-swizzled source chunk
    const bf16_t* src = g + (grow0 + (size_t)(ldrow0 + rr)) * IN_F + kt * 64 + c16 * 8;
    gload_lds16(src, lt + ldrow0 * 64 + tid * 8);   // linear LDS dest
}

#define VMW(N) asm volatile("s_waitcnt vmcnt(" #N ")" ::: "memory")
#define BAR    __builtin_amdgcn_s_barrier()
#define SB     __builtin_amdgcn_sched_barrier(0)

#define RD_A(DST, BUF, MH, KK) do {                                             \
    _Pragma("unroll")                                                           \
    for (int m_ = 0; m_ < 4; ++m_)                                              \
        DST[m_] = *(const bf16x8*)&BUF[(wm * 128 + (MH) * 64 + m_ * 16 + lr) * 64 \
                                       + (((KK) * 4 + hi) ^ (lr & 7)) * 8];     \
} while (0)

#define RD_B(BUF, KK) do {                                                      \
    _Pragma("unroll")                                                           \
    for (int n_ = 0; n_ < 4; ++n_)                                              \
        bq[KK][n_] = *(const bf16x8*)&BUF[(wn * 64 + n_ * 16 + lr) * 64         \
                                       + (((KK) * 4 + hi) ^ (lr & 7)) * 8];     \
} while (0)

#define MM(AF, KK, MH) do {                                                     \
    __builtin_amdgcn_s_setprio(1);                                              \
    _Pragma("unroll")                                                           \
    for (int m_ = 0; m_ < 4; ++m_)                                              \
        _Pragma("unroll")                                                       \
        for (int n_ = 0; n_ < 4; ++n_)                                          \
            acc[(MH) * 4 + m_][n_] = __builtin_amdgcn_mfma_f32_16x16x32_bf16(   \
                AF[m_], bq[KK][n_], acc[(MH) * 4 + m_][n_], 0, 0, 0);           \
    __builtin_amdgcn_s_setprio(0);                                              \
} while (0)

#define TILE(T, CA_, CB_, NA_, NB_) do {                                        \
    const int t1_ = ((T) + 1 < NT) ? (T) + 1 : NT - 1;                          \
    const int t2_ = ((T) + 2 < NT) ? (T) + 2 : NT - 1;                          \
    /* p1: consume (afA,bq0); prefetch (afB,bq1) for p2 */                      \
    stage64(Bm, bcol, NB_, 0,   t1_, tid);                                      \
    stage64(Bm, bcol, NB_, 64,  t1_, tid);                                      \
    RD_A(afB, CA_, 0, 1);                                                       \
    RD_B(CB_, 1);                                                               \
    MM(afA, 0, 0);                                                              \
    VMW(4);                                                                     \
    BAR; SB;                                                                    \
    /* p2: consume (afB,bq1); prefetch afA for p3 */                            \
    stage64(Bm, bcol, NB_, 128, t1_, tid);                                      \
    stage64(Bm, bcol, NB_, 192, t1_, tid);                                      \
    RD_A(afA, CA_, 1, 0);                                                       \
    MM(afB, 1, 0);                                                              \
    VMW(4);                                                                     \
    BAR; SB;                                                                    \
    /* p3: consume (afA,bq0); prefetch afB for p4 */                            \
    stage64(Am, brow, NA_, 64,  t1_, tid);                                      \
    stage64(Am, brow, NA_, 192, t1_, tid);                                      \
    RD_A(afB, CA_, 1, 1);                                                       \
    MM(afA, 0, 1);                                                              \
    VMW(2);                                                                     \
    BAR; SB;                                                                    \
    /* p4: consume (afB,bq1); prefetch (afA,bq0) for p1(t+1) from next bufs */  \
    stage64(Am, brow, CA_, 0,   t2_, tid);                                      \
    stage64(Am, brow, CA_, 128, t2_, tid);                                      \
    RD_A(afA, NA_, 0, 0);                                                       \
    RD_B(NB_, 0);                                                               \
    MM(afB, 1, 1);                                                              \
    BAR; SB;                                                                    \
} while (0)

__global__ __launch_bounds__(512, 2) void gemm256_kernel(
    const bf16_t* __restrict__ Am,   // [MTOT, IN_F]
    const bf16_t* __restrict__ Bm,   // [OUT_F, IN_F]
    float* __restrict__ C)           // [MTOT, OUT_F]
{
    __shared__ bf16_t sA0[256 * 64], sB0[256 * 64], sA1[256 * 64], sB1[256 * 64];

    const int tid  = threadIdx.x;
    const int lane = tid & 63;
    const int lr   = lane & 15;
    const int hi   = lane >> 4;
    const int wave = tid >> 6;
    const int wm   = wave >> 2;      // 0..1
    const int wn   = wave & 3;       // 0..3

    // XCD-aware bijective swizzle (nwg = 1024, % 8 == 0)
    const int bid = blockIdx.x;
    const int swz = (bid & 7) * 128 + (bid >> 3);
    const size_t brow = (size_t)(swz >> 4) * 256;   // 64 row-blocks
    const size_t bcol = (size_t)(swz & 15) * 256;   // 16 col-blocks

    f32x4 acc[8][4];
#pragma unroll
    for (int i = 0; i < 8; ++i)
#pragma unroll
        for (int n = 0; n < 4; ++n)
#pragma unroll
            for (int q = 0; q < 4; ++q) acc[i][n][q] = 0.0f;

    bf16x8 bq[2][4];
    bf16x8 afA[4], afB[4];

    // Prologue: issue in the order that makes the steady-state queue exact:
    // drain A-H0(0)+B(0) with VMW(4), leave [A-H1(0)2, A-H0(1)2] in flight.
    stage64(Am, brow, sA0, 0,   0, tid);   // A-H0(0)
    stage64(Am, brow, sA0, 128, 0, tid);
    stage64(Bm, bcol, sB0, 0,   0, tid);   // B(0)
    stage64(Bm, bcol, sB0, 64,  0, tid);
    stage64(Bm, bcol, sB0, 128, 0, tid);
    stage64(Bm, bcol, sB0, 192, 0, tid);
    stage64(Am, brow, sA0, 64,  0, tid);   // A-H1(0)
    stage64(Am, brow, sA0, 192, 0, tid);
    stage64(Am, brow, sA1, 0,   1, tid);   // A-H0(1)
    stage64(Am, brow, sA1, 128, 1, tid);
    VMW(4);
    BAR; SB;
    // initial fragments for p1(0)'s MFMA (regions drained above, post-BAR)
    RD_A(afA, sA0, 0, 0);
    RD_B(sB0, 0);

    for (int tt = 0; tt < NT; tt += 2) {
        TILE(tt,     sA0, sB0, sA1, sB1);
        TILE(tt + 1, sA1, sB1, sA0, sB0);
    }

    // Epilogue: D col = lane&15, row = (lane>>4)*4 + reg  [m89-verified]
    const size_t r0 = brow + (size_t)wm * 128 + hi * 4;
    const size_t c0 = bcol + (size_t)wn * 64 + lr;
#pragma unroll
    for (int mi = 0; mi < 8; ++mi)
#pragma unroll
        for (int n = 0; n < 4; ++n)
#pragma unroll
            for (int q = 0; q < 4; ++q)
                C[(r0 + mi * 16 + q) * OUT_F + c0 + n * 16] = acc[mi][n][q];
}

// ---------------------------------------------------------------------------
extern "C" void kernel_launch(void* const* d_in, const int* in_sizes, int n_in,
                              void* d_out, int out_size, void* d_ws, size_t ws_size,
                              hipStream_t stream)
{
    const float* x      = (const float*)d_in[0];
    const float* weight = (const float*)d_in[1];
    const float* loraP  = (const float*)d_in[2];
    const float* sigma  = (const float*)d_in[3];
    const float* loraQ  = (const float*)d_in[4];
    float* out = (float*)d_out;

    bf16_t* Wb = (bf16_t*)d_ws;                                      // 32 MiB
    bf16_t* Xb = (bf16_t*)((char*)d_ws + (size_t)OUT_F * IN_F * 2);  // 128 MiB

    fold_weight_kernel<<<(OUT_F * IN_F) / (256 * 4), 256, 0, stream>>>(
        weight, loraP, sigma, loraQ, Wb);

    cvt_x_kernel<<<((size_t)MTOT * IN_F) / (256 * 8), 256, 0, stream>>>(x, Xb);

    gemm256_kernel<<<(MTOT / 256) * (OUT_F / 256), 512, 0, stream>>>(Xb, Wb, out);
}